// Round 2
// baseline (281.795 us; speedup 1.0000x reference)
//
#include <hip/hip_runtime.h>
#include <math.h>

#define NB 4
#define L 512
#define DN 128
#define DP 64
#define H 8
#define HD 32
#define NH (H*HD)        // 256
#define AGG (NH + H*DP)  // 768
#define JC 64

// static device scratch: q,k,v (2048x256 each) + agg (2048x768) = 12MB
__device__ float g_q[NB*L*NH];
__device__ float g_k[NB*L*NH];
__device__ float g_v[NB*L*NH];
__device__ float g_agg[NB*L*AGG];

// ---------------- K1: QKV projection (8 rows / block) ----------------
__global__ __launch_bounds__(256) void k_qkv(const float* __restrict__ x,
    const float* __restrict__ Wq, const float* __restrict__ Wk,
    const float* __restrict__ Wv)
{
    __shared__ float xs[8*DN];
    int t = threadIdx.x;
    int rowbase = blockIdx.x * 8;
    #pragma unroll
    for (int it = 0; it < 4; ++it) {
        int flat = it*256 + t;
        xs[flat] = x[(size_t)rowbase*DN + flat];
    }
    __syncthreads();
    float aq[8], ak[8], av[8];
    #pragma unroll
    for (int r = 0; r < 8; ++r) { aq[r]=0.f; ak[r]=0.f; av[r]=0.f; }
    for (int d = 0; d < DN; ++d) {
        float wq = Wq[d*NH + t];
        float wk = Wk[d*NH + t];
        float wv = Wv[d*NH + t];
        #pragma unroll
        for (int r = 0; r < 8; ++r) {
            float xv = xs[r*DN + d];
            aq[r] = fmaf(xv, wq, aq[r]);
            ak[r] = fmaf(xv, wk, ak[r]);
            av[r] = fmaf(xv, wv, av[r]);
        }
    }
    #pragma unroll
    for (int r = 0; r < 8; ++r) {
        // fold (1/sqrt(HD))*sqrt(0.5) = 0.125 into q
        g_q[(size_t)(rowbase+r)*NH + t] = aq[r] * 0.125f;
        g_k[(size_t)(rowbase+r)*NH + t] = ak[r];
        g_v[(size_t)(rowbase+r)*NH + t] = av[r];
    }
}

// ---------------- K2: flash attention row (1 row / block, 256 thr) ----------------
__global__ __launch_bounds__(256) void k_attn(const float* __restrict__ z,
    const float* __restrict__ Wp)
{
    __shared__ float zc[JC*65];   // z chunk, stride 65 (conflict-free)
    __shared__ float lc[JC*9];    // logits / probs chunk, stride 9
    __shared__ float rf[H];       // per-head rescale factor
    __shared__ float sfin[H];     // final denominators
    __shared__ float wp[DP*H];    // Wp * sqrt(0.5)

    int t = threadIdx.x;
    int lane = t & 63;
    int wv = t >> 6;              // wave 0..3
    int row = blockIdx.x;         // n*L + i
    int n = row >> 9;
    const float* zrow = z + (size_t)row * (L*DP);

    wp[t]       = Wp[t]       * 0.70710678118654752f;
    wp[t + 256] = Wp[t + 256] * 0.70710678118654752f;

    // q fragment for node logits: lane covers dims 4*lane..4*lane+3 (head = lane>>3)
    float q0,q1,q2,q3;
    {
        const float* qr = g_q + (size_t)row * NH + 4*lane;
        q0 = qr[0]; q1 = qr[1]; q2 = qr[2]; q3 = qr[3];
    }

    float accN = 0.f;                 // node feat, c = t (h=t>>5, d=t&31)
    float accP0 = 0.f, accP1 = 0.f;   // pair feat, (hp,p) and (hp+4,p)
    int hN = t >> 5;
    int hp = t >> 6;
    int p  = t & 63;
    // running softmax state (wave wv owns heads wv and wv+4, wave-uniform regs)
    float m0 = -1e30f, s0 = 0.f, m1 = -1e30f, s1 = 0.f;

    for (int c0 = 0; c0 < L; c0 += JC) {
        __syncthreads();   // protect zc/lc from previous iteration readers
        // stage z chunk -> LDS: JC*DP = 4096 floats = 1024 float4 (4 iters x 256 thr)
        {
            const float4* zsrc = (const float4*)(zrow + (size_t)c0*DP);
            #pragma unroll
            for (int it = 0; it < 4; ++it) {
                int f4 = it*256 + t;          // 0..1023
                int j  = f4 >> 4;             // 0..63
                int p4 = (f4 & 15) << 2;      // 0..60
                float4 vz = zsrc[f4];
                float* dst = &zc[j*65 + p4];
                dst[0]=vz.x; dst[1]=vz.y; dst[2]=vz.z; dst[3]=vz.w;
            }
        }
        __syncthreads();
        // 1a: pair logits; wave wv: j = lane, heads wv and wv+4
        {
            float l0 = 0.f, l1 = 0.f;
            const float* zr = &zc[lane*65];
            #pragma unroll 8
            for (int pp = 0; pp < DP; ++pp) {
                float zv = zr[pp];
                l0 = fmaf(zv, wp[pp*H + wv],     l0);
                l1 = fmaf(zv, wp[pp*H + wv + 4], l1);
            }
            lc[lane*9 + wv]     = l0;
            lc[lane*9 + wv + 4] = l1;
        }
        __syncthreads();
        // 1b: node logits; wave wv handles 16 j's, lanes over 256 dims
        {
            for (int jj = 0; jj < 16; ++jj) {
                int j = c0 + wv*16 + jj;
                const float4 kv = *(const float4*)(g_k + (size_t)(n*L + j)*NH + 4*lane);
                float d = q0*kv.x + q1*kv.y + q2*kv.z + q3*kv.w;
                d += __shfl_xor(d, 1);
                d += __shfl_xor(d, 2);
                d += __shfl_xor(d, 4);
                if ((lane & 7) == 0)
                    lc[(wv*16 + jj)*9 + (lane >> 3)] += d;
            }
        }
        __syncthreads();
        // 2: online softmax update; wave wv: heads wv, wv+4
        {
            float va = lc[lane*9 + wv];
            float vb = lc[lane*9 + wv + 4];
            float ma = va, mb = vb;
            #pragma unroll
            for (int o = 32; o > 0; o >>= 1) {
                ma = fmaxf(ma, __shfl_xor(ma, o));
                mb = fmaxf(mb, __shfl_xor(mb, o));
            }
            float mna = fmaxf(m0, ma);
            float mnb = fmaxf(m1, mb);
            float ra = __expf(m0 - mna);
            float rb = __expf(m1 - mnb);
            float ea = __expf(va - mna);
            float eb = __expf(vb - mnb);
            lc[lane*9 + wv]     = ea;
            lc[lane*9 + wv + 4] = eb;
            float sa = ea, sb = eb;
            #pragma unroll
            for (int o = 32; o > 0; o >>= 1) {
                sa += __shfl_xor(sa, o);
                sb += __shfl_xor(sb, o);
            }
            s0 = s0*ra + sa;
            s1 = s1*rb + sb;
            m0 = mna; m1 = mnb;
            if (lane == 0) { rf[wv] = ra; rf[wv+4] = rb; }
        }
        __syncthreads();
        // 3: accumulate node & pair features
        {
            accN  *= rf[hN];
            accP0 *= rf[hp];
            accP1 *= rf[hp+4];
            const float* vbase = g_v + (size_t)(n*L + c0)*NH + t;
            #pragma unroll 8
            for (int j = 0; j < JC; ++j) {
                float vv = vbase[(size_t)j*NH];
                float zv = zc[j*65 + p];
                accN  = fmaf(lc[j*9 + hN],     vv, accN);
                accP0 = fmaf(lc[j*9 + hp],     zv, accP0);
                accP1 = fmaf(lc[j*9 + hp + 4], zv, accP1);
            }
        }
    }
    // finalize: normalize and write agg
    if (lane == 0) { sfin[wv] = s0; sfin[wv+4] = s1; }
    __syncthreads();
    float* arow = g_agg + (size_t)row * AGG;
    arow[t]                    = accN  * (1.f / sfin[hN]);
    arow[NH + hp*DP + p]       = accP0 * (1.f / sfin[hp]);
    arow[NH + (hp+4)*DP + p]   = accP1 * (1.f / sfin[hp+4]);
}

// ---------------- K3: transition + LN + MLP + LN (8 rows / block) ----------------
__global__ __launch_bounds__(256) void k_mlp(const float* __restrict__ x,
    const float* __restrict__ Wt1, const float* __restrict__ bt1,
    const float* __restrict__ g1, const float* __restrict__ b1,
    const float* __restrict__ W2a, const float* __restrict__ b2a,
    const float* __restrict__ W2b, const float* __restrict__ b2b,
    const float* __restrict__ g2, const float* __restrict__ b2,
    float* __restrict__ out)
{
    __shared__ float aggL[8*AGG];    // 24KB
    __shared__ float featsL[8*132];
    __shared__ float h1L[8*132];
    int t = threadIdx.x;
    int tc = t & 127;
    int tr = t >> 7;    // 0/1, wave-uniform
    int lane = t & 63, wv = t >> 6;
    int rowbase = blockIdx.x * 8;

    #pragma unroll
    for (int it = 0; it < 24; ++it) {
        int flat = it*256 + t;
        aggL[flat] = g_agg[(size_t)rowbase*AGG + flat];
    }
    __syncthreads();
    // GEMM1: feats_pre = x + agg @ Wt1 + bt1
    float acc[4] = {0.f,0.f,0.f,0.f};
    for (int kk = 0; kk < AGG; ++kk) {
        float w = Wt1[kk*DN + tc];
        #pragma unroll
        for (int r = 0; r < 4; ++r)
            acc[r] = fmaf(aggL[(tr*4+r)*AGG + kk], w, acc[r]);
    }
    float bt = bt1[tc];
    #pragma unroll
    for (int r = 0; r < 4; ++r) {
        int row = tr*4 + r;
        featsL[row*132 + tc] = acc[r] + bt + x[(size_t)(rowbase+row)*DN + tc];
    }
    __syncthreads();
    // LN1 in place
    for (int rr = 0; rr < 2; ++rr) {
        int row = wv + rr*4;
        float v0 = featsL[row*132 + lane];
        float v1 = featsL[row*132 + 64 + lane];
        float s = v0 + v1, s2 = v0*v0 + v1*v1;
        #pragma unroll
        for (int o = 32; o > 0; o >>= 1) {
            s  += __shfl_xor(s,  o);
            s2 += __shfl_xor(s2, o);
        }
        float mean = s * (1.f/128.f);
        float var  = s2 * (1.f/128.f) - mean*mean;
        float rstd = rsqrtf(var + 1e-5f);
        featsL[row*132 + lane]      = (v0 - mean)*rstd*g1[lane]      + b1[lane];
        featsL[row*132 + 64 + lane] = (v1 - mean)*rstd*g1[64+lane]   + b1[64+lane];
    }
    __syncthreads();
    // GEMM2 + relu
    float acc2[4] = {0.f,0.f,0.f,0.f};
    for (int kk = 0; kk < DN; ++kk) {
        float w = W2a[kk*DN + tc];
        #pragma unroll
        for (int r = 0; r < 4; ++r)
            acc2[r] = fmaf(featsL[(tr*4+r)*132 + kk], w, acc2[r]);
    }
    float ba = b2a[tc];
    #pragma unroll
    for (int r = 0; r < 4; ++r)
        h1L[(tr*4+r)*132 + tc] = fmaxf(acc2[r] + ba, 0.f);
    __syncthreads();
    // GEMM3 + residual
    float acc3[4] = {0.f,0.f,0.f,0.f};
    for (int kk = 0; kk < DN; ++kk) {
        float w = W2b[kk*DN + tc];
        #pragma unroll
        for (int r = 0; r < 4; ++r)
            acc3[r] = fmaf(h1L[(tr*4+r)*132 + kk], w, acc3[r]);
    }
    float bb = b2b[tc];
    #pragma unroll
    for (int r = 0; r < 4; ++r) {
        int row = tr*4 + r;
        featsL[row*132 + tc] = featsL[row*132 + tc] + acc3[r] + bb;
    }
    __syncthreads();
    // LN2 -> out
    for (int rr = 0; rr < 2; ++rr) {
        int row = wv + rr*4;
        float v0 = featsL[row*132 + lane];
        float v1 = featsL[row*132 + 64 + lane];
        float s = v0 + v1, s2 = v0*v0 + v1*v1;
        #pragma unroll
        for (int o = 32; o > 0; o >>= 1) {
            s  += __shfl_xor(s,  o);
            s2 += __shfl_xor(s2, o);
        }
        float mean = s * (1.f/128.f);
        float var  = s2 * (1.f/128.f) - mean*mean;
        float rstd = rsqrtf(var + 1e-5f);
        out[(size_t)(rowbase+row)*DN + lane]      = (v0 - mean)*rstd*g2[lane]    + b2[lane];
        out[(size_t)(rowbase+row)*DN + 64 + lane] = (v1 - mean)*rstd*g2[64+lane] + b2[64+lane];
    }
}

extern "C" void kernel_launch(void* const* d_in, const int* in_sizes, int n_in,
                              void* d_out, int out_size, void* d_ws, size_t ws_size,
                              hipStream_t stream) {
    const float* x   = (const float*)d_in[0];
    const float* z   = (const float*)d_in[1];
    const float* Wq  = (const float*)d_in[2];
    const float* Wk  = (const float*)d_in[3];
    const float* Wv  = (const float*)d_in[4];
    const float* Wp  = (const float*)d_in[5];
    const float* Wt1 = (const float*)d_in[6];
    const float* bt1 = (const float*)d_in[7];
    const float* g1  = (const float*)d_in[8];
    const float* b1  = (const float*)d_in[9];
    const float* W2a = (const float*)d_in[10];
    const float* b2a = (const float*)d_in[11];
    const float* W2b = (const float*)d_in[12];
    const float* b2b = (const float*)d_in[13];
    const float* g2  = (const float*)d_in[14];
    const float* b2  = (const float*)d_in[15];
    float* out = (float*)d_out;

    k_qkv<<<NB*L/8, 256, 0, stream>>>(x, Wq, Wk, Wv);
    k_attn<<<NB*L, 256, 0, stream>>>(z, Wp);
    k_mlp<<<NB*L/8, 256, 0, stream>>>(x, Wt1, bt1, g1, b1,
                                      W2a, b2a, W2b, b2b, g2, b2, out);
}

// Round 3
// 250.879 us; speedup vs baseline: 1.1232x; 1.1232x over previous
//
#include <hip/hip_runtime.h>
#include <math.h>

#define NB 4
#define L 512
#define DN 128
#define DP 64
#define H 8
#define HD 32
#define NH (H*HD)        // 256
#define AGG (NH + H*DP)  // 768
#define JC 64

// static device scratch: q,k,v (2048x256) + agg (2048x768) + node logits (4x8x512x512)
__device__ float g_q[NB*L*NH];
__device__ float g_k[NB*L*NH];
__device__ float g_v[NB*L*NH];
__device__ float g_agg[NB*L*AGG];
__device__ float g_nl[(size_t)NB*H*L*L];   // 33.5MB [n][h][i][j]

// ---------------- K1: QKV projection (8 rows / block) ----------------
__global__ __launch_bounds__(256) void k_qkv(const float* __restrict__ x,
    const float* __restrict__ Wq, const float* __restrict__ Wk,
    const float* __restrict__ Wv)
{
    __shared__ float xs[8*DN];
    int t = threadIdx.x;
    int rowbase = blockIdx.x * 8;
    #pragma unroll
    for (int it = 0; it < 4; ++it) {
        int flat = it*256 + t;
        xs[flat] = x[(size_t)rowbase*DN + flat];
    }
    __syncthreads();
    float aq[8], ak[8], av[8];
    #pragma unroll
    for (int r = 0; r < 8; ++r) { aq[r]=0.f; ak[r]=0.f; av[r]=0.f; }
    for (int d = 0; d < DN; ++d) {
        float wq = Wq[d*NH + t];
        float wk = Wk[d*NH + t];
        float wv = Wv[d*NH + t];
        #pragma unroll
        for (int r = 0; r < 8; ++r) {
            float xv = xs[r*DN + d];
            aq[r] = fmaf(xv, wq, aq[r]);
            ak[r] = fmaf(xv, wk, ak[r]);
            av[r] = fmaf(xv, wv, av[r]);
        }
    }
    #pragma unroll
    for (int r = 0; r < 8; ++r) {
        // fold (1/sqrt(HD))*sqrt(0.5) = 0.125 into q
        g_q[(size_t)(rowbase+r)*NH + t] = aq[r] * 0.125f;
        g_k[(size_t)(rowbase+r)*NH + t] = ak[r];
        g_v[(size_t)(rowbase+r)*NH + t] = av[r];
    }
}

// ---------------- K1.5: node logits GEMM: nl[n,h,i,j] = q[i]·k[j] ----------------
__global__ __launch_bounds__(256) void k_qk()
{
    __shared__ float qs[16*33];
    int t = threadIdx.x;
    int bid = blockIdx.x;            // n*256 + h*32 + itile
    int n = bid >> 8;
    int h = (bid >> 5) & 7;
    int i0 = (bid & 31) << 4;
    if (t < 128) {
        int row = t >> 3, c4 = (t & 7) << 2;
        const float4 qv = *(const float4*)(g_q + (size_t)(n*L + i0 + row)*NH + h*HD + c4);
        float* d = &qs[row*33 + c4];
        d[0]=qv.x; d[1]=qv.y; d[2]=qv.z; d[3]=qv.w;
    }
    __syncthreads();
    for (int jc = 0; jc < L; jc += 256) {
        int j = jc + t;
        float4 kr[8];
        const float4* kb = (const float4*)(g_k + (size_t)(n*L + j)*NH + h*HD);
        #pragma unroll
        for (int c4 = 0; c4 < 8; ++c4) kr[c4] = kb[c4];
        float* outb = g_nl + (size_t)((n*H + h)*L + i0)*L + j;
        #pragma unroll
        for (int i = 0; i < 16; ++i) {
            float acc = 0.f;
            #pragma unroll
            for (int c4 = 0; c4 < 8; ++c4) {
                const float* qp = &qs[i*33 + c4*4];
                acc = fmaf(qp[0], kr[c4].x, acc);
                acc = fmaf(qp[1], kr[c4].y, acc);
                acc = fmaf(qp[2], kr[c4].z, acc);
                acc = fmaf(qp[3], kr[c4].w, acc);
            }
            outb[(size_t)i*L] = acc;
        }
    }
}

// ---------------- K2: flash attention row, 2-barrier pipelined ----------------
__global__ __launch_bounds__(256) void k_attn(const float* __restrict__ z,
    const float* __restrict__ Wp)
{
    __shared__ float zc[2][JC*65];  // double-buffered z chunk, stride 65
    __shared__ float lc[JC*9];      // probs chunk
    __shared__ float rf[H];         // per-head rescale
    __shared__ float sfin[H];
    __shared__ float wp[DP*H];      // Wp * sqrt(0.5)

    int t = threadIdx.x;
    int lane = t & 63;
    int wv = t >> 6;
    int row = blockIdx.x;           // n*L + i
    int n = row >> 9;
    int i = row & 511;
    const float* zrow = z + (size_t)row * (L*DP);

    wp[t]       = Wp[t]       * 0.70710678118654752f;
    wp[t + 256] = Wp[t + 256] * 0.70710678118654752f;

    const float* nl0 = g_nl + (size_t)((n*H + wv    )*L + i)*L;
    const float* nl4 = g_nl + (size_t)((n*H + wv + 4)*L + i)*L;

    float accN = 0.f, accP0 = 0.f, accP1 = 0.f;
    int hN = t >> 5;
    int hp = t >> 6;
    int p  = t & 63;
    float m0 = -1e30f, s0 = 0.f, m1 = -1e30f, s1 = 0.f;

    // prologue: stage chunk 0 into buf 0
    {
        const float4* zsrc = (const float4*)zrow;
        float4 zst[4];
        #pragma unroll
        for (int it = 0; it < 4; ++it) zst[it] = zsrc[it*256 + t];
        #pragma unroll
        for (int it = 0; it < 4; ++it) {
            int f4 = it*256 + t, j = f4 >> 4, p4 = (f4 & 15) << 2;
            float* d = &zc[0][j*65 + p4];
            d[0]=zst[it].x; d[1]=zst[it].y; d[2]=zst[it].z; d[3]=zst[it].w;
        }
    }
    for (int c = 0; c < L/JC; ++c) {
        int cur = c & 1;
        __syncthreads();   // buf[cur] staged & visible; lc/rf free (prev D done)
        // issue next chunk's loads early (latency hides under logit compute)
        float4 zst[4];
        if (c + 1 < L/JC) {
            const float4* zsrc = (const float4*)(zrow + (size_t)(c+1)*JC*DP);
            #pragma unroll
            for (int it = 0; it < 4; ++it) zst[it] = zsrc[it*256 + t];
        }
        // logits for j = lane, heads wv, wv+4 (node part precomputed)
        int jg = c*JC + lane;
        float va = nl0[jg], vb = nl4[jg];
        {
            const float* zr = &zc[cur][lane*65];
            #pragma unroll 8
            for (int pp = 0; pp < DP; ++pp) {
                float zv = zr[pp];
                va = fmaf(zv, wp[pp*H + wv],     va);
                vb = fmaf(zv, wp[pp*H + wv + 4], vb);
            }
        }
        // online softmax fully in registers (wave-uniform m,s)
        float ma = va, mb = vb;
        #pragma unroll
        for (int o = 32; o > 0; o >>= 1) {
            ma = fmaxf(ma, __shfl_xor(ma, o));
            mb = fmaxf(mb, __shfl_xor(mb, o));
        }
        float mna = fmaxf(m0, ma);
        float mnb = fmaxf(m1, mb);
        float ra = __expf(m0 - mna);
        float rb = __expf(m1 - mnb);
        float ea = __expf(va - mna);
        float eb = __expf(vb - mnb);
        lc[lane*9 + wv]     = ea;
        lc[lane*9 + wv + 4] = eb;
        float sa = ea, sb = eb;
        #pragma unroll
        for (int o = 32; o > 0; o >>= 1) {
            sa += __shfl_xor(sa, o);
            sb += __shfl_xor(sb, o);
        }
        s0 = s0*ra + sa;
        s1 = s1*rb + sb;
        m0 = mna; m1 = mnb;
        if (lane == 0) { rf[wv] = ra; rf[wv+4] = rb; }
        // write staged regs into the other buffer (T14 write-late)
        if (c + 1 < L/JC) {
            #pragma unroll
            for (int it = 0; it < 4; ++it) {
                int f4 = it*256 + t, j = f4 >> 4, p4 = (f4 & 15) << 2;
                float* d = &zc[cur^1][j*65 + p4];
                d[0]=zst[it].x; d[1]=zst[it].y; d[2]=zst[it].z; d[3]=zst[it].w;
            }
        }
        __syncthreads();   // lc/rf visible
        // accumulate node & pair features
        accN  *= rf[hN];
        accP0 *= rf[hp];
        accP1 *= rf[hp+4];
        const float* vbase = g_v + (size_t)(n*L + c*JC)*NH + t;
        const float* zcc = zc[cur];
        #pragma unroll 8
        for (int j = 0; j < JC; ++j) {
            float vv = vbase[(size_t)j*NH];
            float zv = zcc[j*65 + p];
            accN  = fmaf(lc[j*9 + hN],     vv, accN);
            accP0 = fmaf(lc[j*9 + hp],     zv, accP0);
            accP1 = fmaf(lc[j*9 + hp + 4], zv, accP1);
        }
    }
    if (lane == 0) { sfin[wv] = s0; sfin[wv+4] = s1; }
    __syncthreads();
    float* arow = g_agg + (size_t)row * AGG;
    arow[t]                    = accN  * (1.f / sfin[hN]);
    arow[NH + hp*DP + p]       = accP0 * (1.f / sfin[hp]);
    arow[NH + (hp+4)*DP + p]   = accP1 * (1.f / sfin[hp+4]);
}

// ---------------- K3: transition + LN + MLP + LN (8 rows / block) ----------------
__global__ __launch_bounds__(256) void k_mlp(const float* __restrict__ x,
    const float* __restrict__ Wt1, const float* __restrict__ bt1,
    const float* __restrict__ g1, const float* __restrict__ b1,
    const float* __restrict__ W2a, const float* __restrict__ b2a,
    const float* __restrict__ W2b, const float* __restrict__ b2b,
    const float* __restrict__ g2, const float* __restrict__ b2,
    float* __restrict__ out)
{
    __shared__ float aggL[8*AGG];    // 24KB
    __shared__ float featsL[8*132];
    __shared__ float h1L[8*132];
    int t = threadIdx.x;
    int tc = t & 127;
    int tr = t >> 7;
    int lane = t & 63, wv = t >> 6;
    int rowbase = blockIdx.x * 8;

    #pragma unroll
    for (int it = 0; it < 24; ++it) {
        int flat = it*256 + t;
        aggL[flat] = g_agg[(size_t)rowbase*AGG + flat];
    }
    __syncthreads();
    float acc[4] = {0.f,0.f,0.f,0.f};
    for (int kk = 0; kk < AGG; ++kk) {
        float w = Wt1[kk*DN + tc];
        #pragma unroll
        for (int r = 0; r < 4; ++r)
            acc[r] = fmaf(aggL[(tr*4+r)*AGG + kk], w, acc[r]);
    }
    float bt = bt1[tc];
    #pragma unroll
    for (int r = 0; r < 4; ++r) {
        int row = tr*4 + r;
        featsL[row*132 + tc] = acc[r] + bt + x[(size_t)(rowbase+row)*DN + tc];
    }
    __syncthreads();
    for (int rr = 0; rr < 2; ++rr) {
        int row = wv + rr*4;
        float v0 = featsL[row*132 + lane];
        float v1 = featsL[row*132 + 64 + lane];
        float s = v0 + v1, s2 = v0*v0 + v1*v1;
        #pragma unroll
        for (int o = 32; o > 0; o >>= 1) {
            s  += __shfl_xor(s,  o);
            s2 += __shfl_xor(s2, o);
        }
        float mean = s * (1.f/128.f);
        float var  = s2 * (1.f/128.f) - mean*mean;
        float rstd = rsqrtf(var + 1e-5f);
        featsL[row*132 + lane]      = (v0 - mean)*rstd*g1[lane]      + b1[lane];
        featsL[row*132 + 64 + lane] = (v1 - mean)*rstd*g1[64+lane]   + b1[64+lane];
    }
    __syncthreads();
    float acc2[4] = {0.f,0.f,0.f,0.f};
    for (int kk = 0; kk < DN; ++kk) {
        float w = W2a[kk*DN + tc];
        #pragma unroll
        for (int r = 0; r < 4; ++r)
            acc2[r] = fmaf(featsL[(tr*4+r)*132 + kk], w, acc2[r]);
    }
    float ba = b2a[tc];
    #pragma unroll
    for (int r = 0; r < 4; ++r)
        h1L[(tr*4+r)*132 + tc] = fmaxf(acc2[r] + ba, 0.f);
    __syncthreads();
    float acc3[4] = {0.f,0.f,0.f,0.f};
    for (int kk = 0; kk < DN; ++kk) {
        float w = W2b[kk*DN + tc];
        #pragma unroll
        for (int r = 0; r < 4; ++r)
            acc3[r] = fmaf(h1L[(tr*4+r)*132 + kk], w, acc3[r]);
    }
    float bb = b2b[tc];
    #pragma unroll
    for (int r = 0; r < 4; ++r) {
        int row = tr*4 + r;
        featsL[row*132 + tc] = featsL[row*132 + tc] + acc3[r] + bb;
    }
    __syncthreads();
    for (int rr = 0; rr < 2; ++rr) {
        int row = wv + rr*4;
        float v0 = featsL[row*132 + lane];
        float v1 = featsL[row*132 + 64 + lane];
        float s = v0 + v1, s2 = v0*v0 + v1*v1;
        #pragma unroll
        for (int o = 32; o > 0; o >>= 1) {
            s  += __shfl_xor(s,  o);
            s2 += __shfl_xor(s2, o);
        }
        float mean = s * (1.f/128.f);
        float var  = s2 * (1.f/128.f) - mean*mean;
        float rstd = rsqrtf(var + 1e-5f);
        out[(size_t)(rowbase+row)*DN + lane]      = (v0 - mean)*rstd*g2[lane]    + b2[lane];
        out[(size_t)(rowbase+row)*DN + 64 + lane] = (v1 - mean)*rstd*g2[64+lane] + b2[64+lane];
    }
}

extern "C" void kernel_launch(void* const* d_in, const int* in_sizes, int n_in,
                              void* d_out, int out_size, void* d_ws, size_t ws_size,
                              hipStream_t stream) {
    const float* x   = (const float*)d_in[0];
    const float* z   = (const float*)d_in[1];
    const float* Wq  = (const float*)d_in[2];
    const float* Wk  = (const float*)d_in[3];
    const float* Wv  = (const float*)d_in[4];
    const float* Wp  = (const float*)d_in[5];
    const float* Wt1 = (const float*)d_in[6];
    const float* bt1 = (const float*)d_in[7];
    const float* g1  = (const float*)d_in[8];
    const float* b1  = (const float*)d_in[9];
    const float* W2a = (const float*)d_in[10];
    const float* b2a = (const float*)d_in[11];
    const float* W2b = (const float*)d_in[12];
    const float* b2b = (const float*)d_in[13];
    const float* g2  = (const float*)d_in[14];
    const float* b2  = (const float*)d_in[15];
    float* out = (float*)d_out;

    k_qkv<<<NB*L/8, 256, 0, stream>>>(x, Wq, Wk, Wv);
    k_qk<<<NB*H*(L/16), 256, 0, stream>>>();
    k_attn<<<NB*L, 256, 0, stream>>>(z, Wp);
    k_mlp<<<NB*L/8, 256, 0, stream>>>(x, Wt1, bt1, g1, b1,
                                      W2a, b2a, W2b, b2b, g2, b2, out);
}